// Round 2
// baseline (620.094 us; speedup 1.0000x reference)
//
#include <hip/hip_runtime.h>
#include <math.h>

// NoisyTopKRouter: B=4, T=4096, C=2048, E=64, K=8; rows = B*T = 16384.
// fp32 VALU GEMM (no fp32 MFMA on CDNA4) + fused epilogue.
// Near-tie rank boundaries (gap < TAU) are repaired with exact f64 recompute
// so the top-k ordering matches the float64 numpy golden reference.

#define CDIM   2048
#define EDIM   64
#define NOUT   128   // 64 route + 64 noise logits per row
#define TOPK   8
#define ROWS_PB 32   // rows per block
#define KT     64    // k-tile
#define XPAD   68    // padded x-tile leading dim (floats)
#define TAU    1e-3f // near-tie repair threshold (>=50x worst-case fp32 error)

__global__ __launch_bounds__(256, 2)
void noisy_topk_router(const float* __restrict__ x,
                       const float* __restrict__ w_route,
                       const float* __restrict__ w_noise,
                       const float* __restrict__ noise,
                       float* __restrict__ out_probs,
                       float* __restrict__ out_idx)
{
    __shared__ float xs[ROWS_PB * XPAD];   // x tile
    __shared__ float ws[NOUT * KT];        // w tile (swizzled quads)

    const int tid  = (int)threadIdx.x;
    const int row0 = (int)blockIdx.x * ROWS_PB;
    const int eg   = tid & 31;   // expert group: experts eg + 32*j
    const int rg   = tid >> 5;   // row group:   rows    rg*4 + i
    const int sw   = eg & 15;

    float4 acc[4][4];
    #pragma unroll
    for (int i = 0; i < 4; ++i)
        #pragma unroll
        for (int j = 0; j < 4; ++j)
            acc[i][j] = make_float4(0.f, 0.f, 0.f, 0.f);

    for (int kt0 = 0; kt0 < CDIM; kt0 += KT) {
        __syncthreads();
        #pragma unroll
        for (int s = 0; s < 2; ++s) {
            int q  = tid + 256 * s;
            int r  = q >> 4;
            int kq = q & 15;
            const float4 v = *(const float4*)(x + (size_t)(row0 + r) * CDIM + kt0 + (kq << 2));
            *(float4*)(xs + r * XPAD + (kq << 2)) = v;
        }
        #pragma unroll
        for (int s = 0; s < 8; ++s) {
            int q  = tid + 256 * s;
            int e  = q >> 4;
            int kq = q & 15;
            const float* src = (e < EDIM) ? (w_route + (size_t)e * CDIM)
                                          : (w_noise + (size_t)(e - EDIM) * CDIM);
            const float4 v = *(const float4*)(src + kt0 + (kq << 2));
            *(float4*)(ws + e * KT + ((kq ^ (e & 15)) << 2)) = v;
        }
        __syncthreads();
        #pragma unroll
        for (int kq = 0; kq < 16; ++kq) {
            float4 xv[4], wv[4];
            #pragma unroll
            for (int i = 0; i < 4; ++i)
                xv[i] = *(const float4*)(xs + (rg * 4 + i) * XPAD + (kq << 2));
            const int kqs = ((kq ^ sw) << 2);
            #pragma unroll
            for (int j = 0; j < 4; ++j)
                wv[j] = *(const float4*)(ws + (eg + 32 * j) * KT + kqs);
            #pragma unroll
            for (int i = 0; i < 4; ++i)
                #pragma unroll
                for (int j = 0; j < 4; ++j) {
                    acc[i][j].x = fmaf(xv[i].x, wv[j].x, acc[i][j].x);
                    acc[i][j].y = fmaf(xv[i].y, wv[j].y, acc[i][j].y);
                    acc[i][j].z = fmaf(xv[i].z, wv[j].z, acc[i][j].z);
                    acc[i][j].w = fmaf(xv[i].w, wv[j].w, acc[i][j].w);
                }
        }
    }

    __syncthreads();
    float* lg = ws;   // 32 x 129 logits
    #pragma unroll
    for (int i = 0; i < 4; ++i)
        #pragma unroll
        for (int j = 0; j < 4; ++j) {
            float v = (acc[i][j].x + acc[i][j].y) + (acc[i][j].z + acc[i][j].w);
            lg[(rg * 4 + i) * 129 + (eg + 32 * j)] = v;
        }
    __syncthreads();

    const int wave = tid >> 6;
    const int lane = tid & 63;   // lane == expert index
    for (int rr = 0; rr < 8; ++rr) {
        const int r    = wave * 8 + rr;
        const int grow = row0 + r;
        const float route = lg[r * 129 + lane];
        const float nz    = lg[r * 129 + EDIM + lane];
        const float nv    = noise[(size_t)grow * EDIM + lane];
        const float sp = fmaxf(nz, 0.f) + log1pf(expf(-fabsf(nz)));
        const float nl = route + nv * sp;

        // 9-iteration scan: top-8 ranks + the 9th value, tracking min adjacent gap
        float work = nl;
        int   rank = -1;
        float m = 0.f, prev = 0.f, min_gap = INFINITY;
        #pragma unroll
        for (int t = 0; t <= TOPK; ++t) {
            float bv = work;
            int   bi = lane;
            #pragma unroll
            for (int off = 32; off >= 1; off >>= 1) {
                float ov = __shfl_xor(bv, off, 64);
                int   oi = __shfl_xor(bi, off, 64);
                if (ov > bv || (ov == bv && oi < bi)) { bv = ov; bi = oi; }
            }
            if (t == 0) m = bv; else min_gap = fminf(min_gap, prev - bv);
            prev = bv;
            if (lane == bi) {
                if (t < TOPK) rank = t;
                work = -INFINITY;
            }
        }

        if (min_gap >= TAU) {
            // unambiguous ordering: emit from fp32 path
            if (rank >= 0) out_idx[(size_t)grow * TOPK + rank] = (float)lane;
            float ev = (rank >= 0) ? expf(nl - m) : 0.f;
            float s  = ev;
            #pragma unroll
            for (int off = 32; off >= 1; off >>= 1) s += __shfl_xor(s, off, 64);
            out_probs[(size_t)grow * EDIM + lane] = ev / s;
        } else {
            // near-tie: recompute this row's 128 logits with exact f64 accumulation
            const float* xr = x + (size_t)grow * CDIM;
            const float* wr = w_route + (size_t)lane * CDIM;
            const float* wn = w_noise + (size_t)lane * CDIM;
            double ar = 0.0, an = 0.0;
            for (int k = 0; k < CDIM; k += 4) {
                const float4 xv = *(const float4*)(xr + k);
                const float4 rv = *(const float4*)(wr + k);
                const float4 nq = *(const float4*)(wn + k);
                ar = fma((double)xv.x, (double)rv.x, ar);
                ar = fma((double)xv.y, (double)rv.y, ar);
                ar = fma((double)xv.z, (double)rv.z, ar);
                ar = fma((double)xv.w, (double)rv.w, ar);
                an = fma((double)xv.x, (double)nq.x, an);
                an = fma((double)xv.y, (double)nq.y, an);
                an = fma((double)xv.z, (double)nq.z, an);
                an = fma((double)xv.w, (double)nq.w, an);
            }
            const double spd  = fmax(an, 0.0) + log1p(exp(-fabs(an)));
            const double nl64 = ar + (double)nv * spd;

            double workd = nl64;
            int    rank64 = -1;
            double m64 = 0.0;
            #pragma unroll
            for (int t = 0; t < TOPK; ++t) {
                double bv = workd;
                int    bi = lane;
                #pragma unroll
                for (int off = 32; off >= 1; off >>= 1) {
                    double ov = __shfl_xor(bv, off, 64);
                    int    oi = __shfl_xor(bi, off, 64);
                    if (ov > bv || (ov == bv && oi < bi)) { bv = ov; bi = oi; }
                }
                if (t == 0) m64 = bv;
                if (lane == bi) {
                    rank64 = t;
                    workd = -INFINITY;
                    out_idx[(size_t)grow * TOPK + t] = (float)lane;
                }
            }
            float ev = (rank64 >= 0) ? expf((float)(nl64 - m64)) : 0.f;
            float s  = ev;
            #pragma unroll
            for (int off = 32; off >= 1; off >>= 1) s += __shfl_xor(s, off, 64);
            out_probs[(size_t)grow * EDIM + lane] = ev / s;
        }
    }
}

extern "C" void kernel_launch(void* const* d_in, const int* in_sizes, int n_in,
                              void* d_out, int out_size, void* d_ws, size_t ws_size,
                              hipStream_t stream)
{
    const float* x       = (const float*)d_in[0];
    const float* w_route = (const float*)d_in[1];
    const float* w_noise = (const float*)d_in[2];
    const float* noise   = (const float*)d_in[3];

    const int n_rows = in_sizes[0] / CDIM;                // 16384
    float* out_probs = (float*)d_out;                     // (B,T,E) fp32
    float* out_idx   = out_probs + (size_t)n_rows * EDIM; // (B,T,K) as fp32 values

    dim3 grid(n_rows / ROWS_PB);
    dim3 block(256);
    hipLaunchKernelGGL(noisy_topk_router, grid, block, 0, stream,
                       x, w_route, w_noise, noise, out_probs, out_idx);
}